// Round 11
// baseline (24.525 us; speedup 1.0000x reference)
//
#include <hip/hip_runtime.h>

#define N 4096
#define M 1024
#define D 64
#define MT 16                             // m-values per thread
#define SPLITS 16                         // N-chunks (champion config)
#define ROWS_PER_BLOCK (N / SPLITS)       // 256
#define SLAB 64                           // rows per LDS staging slab
#define NSLAB (ROWS_PER_BLOCK / SLAB)     // 4
#define SITES (M * D)                     // 65536
#define K2_BLOCKS 64

// Register-only 3-input min (v_min3_f32), minnum semantics = fminf twice.
__device__ __forceinline__ float min3f(float a, float b, float c) {
    float d;
    asm("v_min3_f32 %0, %1, %2, %3" : "=v"(d) : "v"(a), "v"(b), "v"(c));
    return d;
}

// K1: champion math/geometry, but z is staged through LDS:
// per 64-row slab, 256 threads cooperatively load 16 KB as coalesced float4
// (16 wide VMEM insts/thread total vs 64 scalar stride-256B loads), then
// wave w computes its 16 rows from LDS (2-way bank aliasing = free).
// Same row-set per block + min order-independence -> bit-identical pout.
__global__ __launch_bounds__(256) void k_minpart(const float* __restrict__ z,
                                                 const float* __restrict__ e,
                                                 const int* __restrict__ idx,
                                                 float* __restrict__ pout,
                                                 float* __restrict__ out,
                                                 int* __restrict__ counter) {
    const int bid = blockIdx.x;
    if (bid == 0 && threadIdx.x == 0) *counter = 0;   // reset for K2, every call

    // fused elementwise outputs: 256 elements per block
    {
        const int i = bid * 256 + (int)threadIdx.x;
        const float zv = z[i];
        const int row = i >> 6, dd = i & 63;
        out[1 + i] = (dd < idx[row]) ? zv : 0.0f;   // z_masked
        out[1 + N * D + i] = zv;                    // z_copy
    }

    const int mt   = bid & 63;    // m-tile
    const int s    = bid >> 6;    // split
    const int lane = threadIdx.x & 63;
    const int w    = threadIdx.x >> 6;
    const int m0   = mt * MT;

    float n2e[MT];
#pragma unroll
    for (int j = 0; j < MT; ++j) n2e[j] = -2.0f * e[(m0 + j) * D + lane];

    float acc[MT];
#pragma unroll
    for (int j = 0; j < MT; ++j) acc[j] = 3.4e38f;

    __shared__ float zs[SLAB * D];   // 16 KB slab; reused as reduce buffer

    const float4* zsrc = (const float4*)(z + s * ROWS_PER_BLOCK * D);
    for (int sl = 0; sl < NSLAB; ++sl) {
        __syncthreads();   // previous slab fully consumed by all waves
        // stage 64 rows = 1024 float4; 4 per thread, fully coalesced
        float4* dst4 = (float4*)zs;
        const float4* s4 = zsrc + sl * (SLAB * D / 4);
#pragma unroll
        for (int k = 0; k < 4; ++k)
            dst4[(int)threadIdx.x + k * 256] = s4[(int)threadIdx.x + k * 256];
        __syncthreads();
        // wave w consumes slab rows [w*16, w*16+16)
        const float* zw = zs + (w * 16) * D + lane;
#pragma unroll
        for (int r4 = 0; r4 < 4; ++r4) {   // 4 four-row batches
            const float za = zw[(4 * r4 + 0) * D];
            const float zb = zw[(4 * r4 + 1) * D];
            const float zc = zw[(4 * r4 + 2) * D];
            const float zd = zw[(4 * r4 + 3) * D];
            const float za2 = za * za, zb2 = zb * zb;
            const float zc2 = zc * zc, zd2 = zd * zd;
#pragma unroll
            for (int j = 0; j < MT; ++j) {
                const float t1 = fmaf(n2e[j], za, za2);
                const float t2 = fmaf(n2e[j], zb, zb2);
                const float t3 = fmaf(n2e[j], zc, zc2);
                const float t4 = fmaf(n2e[j], zd, zd2);
                acc[j] = min3f(acc[j], min3f(t1, t2, t3), t4);
            }
        }
    }

    // cross-wave min reduce, reusing zs as [4][MT*64] (16 KB)
    __syncthreads();   // all waves done reading the last slab
    float* red = zs;
#pragma unroll
    for (int j = 0; j < MT; ++j) red[w * (MT * 64) + j * 64 + lane] = acc[j];
    __syncthreads();
    for (int p = threadIdx.x; p < MT * 64; p += 256) {
        const float v = fminf(fminf(red[0 * 1024 + p], red[1 * 1024 + p]),
                              fminf(red[2 * 1024 + p], red[3 * 1024 + p]));
        pout[s * SITES + m0 * 64 + p] = v;   // coalesced, champion layout
    }
}

// K2: champion form, bit-identical. min over 16 splits + e^2, sum; 64 blocks,
// 4 sites/thread; deterministic last-block finish: 64 PARALLEL coherent reads
// + fixed-order shuffle tree.
__global__ __launch_bounds__(256) void k_minsum(const float* __restrict__ pout,
                                                const float* __restrict__ e,
                                                float* __restrict__ bsums,
                                                int* __restrict__ counter,
                                                float* __restrict__ out) {
    const int t = blockIdx.x * 256 + (int)threadIdx.x;  // 16384 threads
    float local = 0.0f;
#pragma unroll
    for (int k = 0; k < 4; ++k) {
        const int site = t + k * 16384;
        float v = 3.4e38f;
#pragma unroll
        for (int si = 0; si < SPLITS; ++si)
            v = fminf(v, pout[si * SITES + site]);
        const float ev = e[site];
        local += v + ev * ev;
    }
#pragma unroll
    for (int off = 32; off > 0; off >>= 1)
        local += __shfl_down(local, off, 64);
    __shared__ float wsum[4];
    __shared__ int is_last;
    const int lane = threadIdx.x & 63, w = threadIdx.x >> 6;
    if (lane == 0) wsum[w] = local;
    __syncthreads();
    if (threadIdx.x == 0) {
        atomicExch(&bsums[blockIdx.x], (wsum[0] + wsum[1]) + (wsum[2] + wsum[3]));
        __threadfence();
        is_last = (atomicAdd(counter, 1) == K2_BLOCKS - 1);
    }
    __syncthreads();
    if (is_last && threadIdx.x < 64) {
        __threadfence();
        float v = atomicAdd(&bsums[threadIdx.x], 0.0f);  // 64 parallel reads
#pragma unroll
        for (int off = 32; off > 0; off >>= 1)
            v += __shfl_down(v, off, 64);
        if (threadIdx.x == 0) out[0] = v * (1.0f / SITES);
    }
}

extern "C" void kernel_launch(void* const* d_in, const int* in_sizes, int n_in,
                              void* d_out, int out_size, void* d_ws, size_t ws_size,
                              hipStream_t stream) {
    const float* z   = (const float*)d_in[0];
    const float* e   = (const float*)d_in[1];
    const int*   idx = (const int*)d_in[2];
    float* out = (float*)d_out;

    float* pout    = (float*)d_ws;                       // 4 MB partials
    float* bsums   = (float*)d_ws + SPLITS * SITES;      // 64 floats
    int*   counter = (int*)(bsums + K2_BLOCKS);

    k_minpart<<<64 * SPLITS, 256, 0, stream>>>(z, e, idx, pout, out, counter);
    k_minsum<<<K2_BLOCKS, 256, 0, stream>>>(pout, e, bsums, counter, out);
}